// Round 4
// baseline (439.062 us; speedup 1.0000x reference)
//
#include <hip/hip_runtime.h>
#include <stdint.h>

// Problem dims (fixed by reference)
#define BB 4
#define SS 2048
#define EE 512
#define HH 1024
// token rows = 8192, ext rows = 2048

typedef _Float16 f16;
typedef __attribute__((ext_vector_type(8))) _Float16 f16x8;
typedef __attribute__((ext_vector_type(4))) _Float16 f16x4;
typedef __attribute__((ext_vector_type(4))) float f32x4;

__device__ __forceinline__ void async16(void* lds, const void* g) {
  __builtin_amdgcn_global_load_lds(
      (const __attribute__((address_space(1))) unsigned int*)g,
      (__attribute__((address_space(3))) unsigned int*)lds, 16, 0, 0);
}

// ---------------------------------------------------------------------------
// Core 128x128 BT-GEMM: C = A * B^T, row-major fp16, B row stride = ld.
// TERMS=1: acc += A*Bh          (2 LDS buffers)
// TERMS=2: acc += A*Bh + A*Bl   (3 buffers; B split hi+lo)
// TERMS=3: acc += Ah*Bh + Ah*Bl + Al*Bh  (4 buffers; both split)
// LDS XOR-swizzle: row r's 16B k-chunk c stored at c ^ ((r>>1)&3) ->
// conflict-free ds_read_b128 (verified R2: SQ_LDS_BANK_CONFLICT 1.2e7 -> 0).
// ---------------------------------------------------------------------------
template <int TERMS>
__device__ __forceinline__ void gemm_core(
    const f16* Ah, const f16* Al, const f16* Bh, const f16* Bl, int K, int ld,
    f16* lAh, f16* lAl, f16* lBh, f16* lBl, f32x4 acc[4][4]) {
  const int tid = threadIdx.x;
  const int wave = tid >> 6;
  const int lane = tid & 63;
  const int lrow = lane >> 2;  // 0..15 within 16-row staging group
  const int lcol = (((lane & 3) ^ ((lane >> 3) & 3))) * 8;  // swizzled source chunk
  const int waveM = (wave >> 1) * 64;
  const int waveN = (wave & 1) * 64;
  const int frow = lane & 15;
  const int fk = ((lane >> 4) ^ ((frow >> 1) & 3)) * 8;  // swizzled fragment pos

  for (int k0 = 0; k0 < K; k0 += 32) {
    __syncthreads();  // previous iteration's LDS reads done
#pragma unroll
    for (int i = 0; i < 2; ++i) {
      const int r0 = (wave * 2 + i) * 16;
      const size_t goff = (size_t)(r0 + lrow) * ld + (k0 + lcol);
      async16(&lAh[r0 * 32], Ah + goff);
      async16(&lBh[r0 * 32], Bh + goff);
      if (TERMS >= 2) async16(&lBl[r0 * 32], Bl + goff);
      if (TERMS >= 3) async16(&lAl[r0 * 32], Al + goff);
    }
    __syncthreads();  // staging complete

    f16x8 a[4], bh[4], bl[4], al[4];
#pragma unroll
    for (int i = 0; i < 4; ++i) {
      a[i] = *(const f16x8*)&lAh[(waveM + i * 16 + frow) * 32 + fk];
      bh[i] = *(const f16x8*)&lBh[(waveN + i * 16 + frow) * 32 + fk];
      if (TERMS >= 2) bl[i] = *(const f16x8*)&lBl[(waveN + i * 16 + frow) * 32 + fk];
      if (TERMS >= 3) al[i] = *(const f16x8*)&lAl[(waveM + i * 16 + frow) * 32 + fk];
    }
#pragma unroll
    for (int i = 0; i < 4; ++i)
#pragma unroll
      for (int j = 0; j < 4; ++j) {
        acc[i][j] = __builtin_amdgcn_mfma_f32_16x16x32_f16(a[i], bh[j], acc[i][j], 0, 0, 0);
        if (TERMS >= 2)
          acc[i][j] = __builtin_amdgcn_mfma_f32_16x16x32_f16(a[i], bl[j], acc[i][j], 0, 0, 0);
        if (TERMS >= 3)
          acc[i][j] = __builtin_amdgcn_mfma_f32_16x16x32_f16(al[i], bh[j], acc[i][j], 0, 0, 0);
      }
  }
}

// ---------------------------------------------------------------------------
// Vectorized fp16 epilogue: fragments -> LDS tile (row-major, 72-f16 padded
// rows = 144B, 16B-aligned) -> coalesced f16x8 global stores. Two col-passes
// (waveN group p); optional lo plane (val - (f16)val) for split outputs.
// base = row0*ldOut + col0. tl needs 128*72 f16 = 18 KB.
// ---------------------------------------------------------------------------
__device__ __forceinline__ void epi_rowmajor(
    f16* __restrict__ hi, f16* __restrict__ lo, size_t base, size_t ldOut,
    const f32x4 acc[4][4], const float bias[4], f16* tl) {
  const int tid = threadIdx.x, wave = tid >> 6, lane = tid & 63;
  const int waveM = (wave >> 1) * 64;
  const int colIn16 = lane & 15, quad = lane >> 4;
  const int npl = lo ? 2 : 1;
#pragma unroll
  for (int p = 0; p < 2; ++p) {
    for (int pl = 0; pl < npl; ++pl) {
      __syncthreads();
      if ((wave & 1) == p) {
#pragma unroll
        for (int i = 0; i < 4; ++i)
#pragma unroll
          for (int j = 0; j < 4; ++j)
#pragma unroll
            for (int r = 0; r < 4; ++r) {
              const int row = waveM + i * 16 + quad * 4 + r;
              const int col = j * 16 + colIn16;
              const float val = acc[i][j][r] + bias[j];
              const f16 h = (f16)val;
              tl[row * 72 + col] = pl ? (f16)(val - (float)h) : h;
            }
      }
      __syncthreads();
      f16* d = pl ? lo : hi;
      for (int c = tid; c < 1024; c += 256) {
        const int row = c >> 3, ch = c & 7;
        const f16x8 v = *(const f16x8*)&tl[row * 72 + ch * 8];
        *(f16x8*)&d[base + (size_t)row * ldOut + p * 64 + ch * 8] = v;
      }
    }
  }
}

// Transposed epilogue for veT: LDS filled transposed ([64 cols][136-row pad]),
// read back row-major along e. dst pre-offset to (bb*HH + c2base)*EE + e0.
__device__ __forceinline__ void epi_transposed(
    f16* __restrict__ dst, const f32x4 acc[4][4], const float bias[4], f16* tl) {
  const int tid = threadIdx.x, wave = tid >> 6, lane = tid & 63;
  const int waveM = (wave >> 1) * 64;
  const int colIn16 = lane & 15, quad = lane >> 4;
#pragma unroll
  for (int p = 0; p < 2; ++p) {
    __syncthreads();
    if ((wave & 1) == p) {
#pragma unroll
      for (int i = 0; i < 4; ++i)
#pragma unroll
        for (int j = 0; j < 4; ++j)
#pragma unroll
          for (int r = 0; r < 4; ++r) {
            const int row = waveM + i * 16 + quad * 4 + r;
            const int colL = j * 16 + colIn16;
            tl[colL * 136 + row] = (f16)(acc[i][j][r] + bias[j]);
          }
    }
    __syncthreads();
    for (int c = tid; c < 1024; c += 256) {
      const int colL = c >> 4, ch = c & 15;
      const f16x8 v = *(const f16x8*)&tl[colL * 136 + ch * 8];
      *(f16x8*)&dst[(size_t)(p * 64 + colL) * EE + ch * 8] = v;
    }
  }
}

// fp32 -> fp16 cast (A-side operands need no lo plane)
__global__ __launch_bounds__(256) void cast_kernel(const float* __restrict__ x,
                                                   f16* __restrict__ h, int n4) {
  const int i = blockIdx.x * 256 + threadIdx.x;
  if (i >= n4) return;
  const float4 v = ((const float4*)x)[i];
  f16x4 o;
  o.x = (f16)v.x; o.y = (f16)v.y; o.z = (f16)v.z; o.w = (f16)v.w;
  ((f16x4*)h)[i] = o;
}

// Transpose-split W: Wt[n'][k] = W_{n'>>10}[k][n'&1023], n' in [0,3072), fp16 hi+lo
__global__ void wsplit_kernel(const float* __restrict__ Wq, const float* __restrict__ Wk,
                              const float* __restrict__ Wv, f16* __restrict__ wt_hi,
                              f16* __restrict__ wt_lo) {
  __shared__ float tile[32][33];
  const int k0 = blockIdx.x * 32;
  const int n0g = blockIdx.y * 32;
  const int which = n0g >> 10;
  const float* W = which == 0 ? Wq : (which == 1 ? Wk : Wv);
  const int n0 = n0g & 1023;
  const int tx = threadIdx.x, ty = threadIdx.y;
#pragma unroll
  for (int i = 0; i < 32; i += 8)
    tile[ty + i][tx] = W[(size_t)(k0 + ty + i) * 1024 + n0 + tx];
  __syncthreads();
#pragma unroll
  for (int i = 0; i < 32; i += 8) {
    const int np = n0g + ty + i;
    const float v = tile[tx][ty + i];
    const size_t idx = (size_t)np * 1024 + k0 + tx;
    const f16 h = (f16)v;
    wt_hi[idx] = h;
    wt_lo[idx] = (f16)(v - (float)h);
  }
}

// ---------------------------------------------------------------------------
// Projection GEMM: rows = [8192 token | 2048 ext], cols = [q|k|v].
// Split (B=wt hi+lo): q (token only) and ext-k. Plain: token-k (kt is only
// used in the self-dot -> no lo needed) and all v. Ext rows skip q.
// ---------------------------------------------------------------------------
__global__ __launch_bounds__(256, 4) void proj_kernel(
    const f16* __restrict__ xh, const f16* __restrict__ xe,
    const f16* __restrict__ wt_hi, const f16* __restrict__ wt_lo,
    const float* __restrict__ bq, const float* __restrict__ bk,
    const float* __restrict__ bv, f16* __restrict__ q_hi, f16* __restrict__ q_lo,
    f16* __restrict__ kt, f16* __restrict__ vt,
    f16* __restrict__ ke_hi, f16* __restrict__ ke_lo, f16* __restrict__ veT) {
  const int ntile = blockIdx.x;  // 0..23 (3072 cols)
  const int mtile = blockIdx.y;  // 0..79 (10240 rows)
  const bool extRows = (mtile >= 64);
  if (extRows && ntile < 8) return;  // ext rows need no q

  __shared__ f16 lds[3 * 4096];  // 24 KB: staging (2-3 x 8KB) then epilogue tile

  const f16* A = extRows ? xe : xh;
  const int rowA = (extRows ? (mtile - 64) : mtile) * 128;
  const int rowB = ntile * 128;
  const bool split = (ntile < 8) || (extRows && ntile < 16);

  f32x4 acc[4][4];
#pragma unroll
  for (int i = 0; i < 4; ++i)
#pragma unroll
    for (int j = 0; j < 4; ++j)
#pragma unroll
      for (int r = 0; r < 4; ++r) acc[i][j][r] = 0.0f;

  if (split)
    gemm_core<2>(A + (size_t)rowA * HH, nullptr, wt_hi + (size_t)rowB * HH,
                 wt_lo + (size_t)rowB * HH, HH, HH,
                 lds, nullptr, lds + 4096, lds + 8192, acc);
  else
    gemm_core<1>(A + (size_t)rowA * HH, nullptr, wt_hi + (size_t)rowB * HH,
                 nullptr, HH, HH, lds, nullptr, lds + 4096, nullptr, acc);

  const int wave = threadIdx.x >> 6, lane = threadIdx.x & 63;
  const int waveN = (wave & 1) * 64, colIn16 = lane & 15;
  float bias[4];
#pragma unroll
  for (int j = 0; j < 4; ++j) {
    const int c = ntile * 128 + waveN + j * 16 + colIn16;
    bias[j] = c < 1024 ? bq[c] : (c < 2048 ? bk[c - 1024] : bv[c - 2048]);
  }

  if (ntile < 8) {  // q (token rows only), hi+lo
    epi_rowmajor(q_hi, q_lo, (size_t)(mtile * 128) * HH + ntile * 128, HH,
                 acc, bias, lds);
  } else if (ntile < 16) {  // k
    if (!extRows)
      epi_rowmajor(kt, nullptr, (size_t)(mtile * 128) * HH + (ntile - 8) * 128, HH,
                   acc, bias, lds);
    else
      epi_rowmajor(ke_hi, ke_lo,
                   (size_t)((mtile - 64) * 128) * HH + (ntile - 8) * 128, HH,
                   acc, bias, lds);
  } else {  // v
    if (!extRows)
      epi_rowmajor(vt, nullptr, (size_t)(mtile * 128) * HH + (ntile - 16) * 128, HH,
                   acc, bias, lds);
    else {
      const int ge0 = (mtile - 64) * 128;
      const int bb = ge0 >> 9, e0 = ge0 & 511;
      epi_transposed(veT + ((size_t)bb * HH + (ntile - 16) * 128) * EE + e0,
                     acc, bias, lds);
    }
  }
}

// Score GEMM, split-K, 3-term: s_part[kh][b][s][e] = q[b,s,kh*512:] . ke[...]
// acc = qh*keh + qh*kel + ql*keh (dropped ql*kel ~ 1e-7 relative).
__global__ __launch_bounds__(256, 4) void score_kernel(
    const f16* __restrict__ q_hi, const f16* __restrict__ q_lo,
    const f16* __restrict__ ke_hi, const f16* __restrict__ ke_lo,
    float* __restrict__ s_part) {
  const int b = blockIdx.z & 3;
  const int khalf = blockIdx.z >> 2;
  const int mtile = blockIdx.y;  // 0..15
  const int ntile = blockIdx.x;  // 0..3
  __shared__ f16 lds[4 * 4096];
  const size_t aoff = ((size_t)b * SS + mtile * 128) * HH + khalf * 512;
  const size_t boff = ((size_t)b * EE + ntile * 128) * HH + khalf * 512;

  f32x4 acc[4][4];
#pragma unroll
  for (int i = 0; i < 4; ++i)
#pragma unroll
    for (int j = 0; j < 4; ++j)
#pragma unroll
      for (int r = 0; r < 4; ++r) acc[i][j][r] = 0.0f;

  gemm_core<3>(q_hi + aoff, q_lo + aoff, ke_hi + boff, ke_lo + boff, 512, HH,
               lds, lds + 4096, lds + 8192, lds + 12288, acc);

  float* dst = s_part + (size_t)khalf * BB * SS * EE;
  const int tid = threadIdx.x, wave = tid >> 6, lane = tid & 63;
  const int waveM = (wave >> 1) * 64, waveN = (wave & 1) * 64;
  const int colIn16 = lane & 15, rowQuad = (lane >> 4) * 4;
  // fp32 scalar stores: 16 lanes x 4B = 64B full segments -> no write amp.
#pragma unroll
  for (int j = 0; j < 4; ++j) {
    const int e = ntile * 128 + waveN + j * 16 + colIn16;
#pragma unroll
    for (int i = 0; i < 4; ++i)
#pragma unroll
      for (int r = 0; r < 4; ++r) {
        const int s = mtile * 128 + waveM + i * 16 + rowQuad + r;
        dst[((size_t)b * SS + s) * EE + e] = acc[i][j][r];
      }
  }
}

// Fused selfdot + softmax: s_self = (q_hi+q_lo).kt (fp32 accumulate),
// softmax over [s_self, s_part0+s_part1]; probs -> fp16, p_self -> fp32.
__global__ __launch_bounds__(256) void softmax_kernel(
    const f16* __restrict__ q_hi, const f16* __restrict__ q_lo,
    const f16* __restrict__ kt, const float* __restrict__ s_part,
    f16* __restrict__ probs, float* __restrict__ p_self) {
  const int t = blockIdx.x * 4 + (threadIdx.x >> 6);
  const int lane = threadIdx.x & 63;

  // selfdot
  const size_t base = (size_t)t * HH;
  float ss = 0.f;
#pragma unroll
  for (int it = 0; it < 4; ++it) {
    const int off = it * 256 + lane * 4;
    const f16x4 qh = *(const f16x4*)&q_hi[base + off];
    const f16x4 ql = *(const f16x4*)&q_lo[base + off];
    const f16x4 kh = *(const f16x4*)&kt[base + off];
    ss += ((float)qh.x + (float)ql.x) * (float)kh.x;
    ss += ((float)qh.y + (float)ql.y) * (float)kh.y;
    ss += ((float)qh.z + (float)ql.z) * (float)kh.z;
    ss += ((float)qh.w + (float)ql.w) * (float)kh.w;
  }
#pragma unroll
  for (int m = 32; m > 0; m >>= 1) ss += __shfl_xor(ss, m, 64);

  // softmax over 1 + 512
  const float* r0 = s_part + (size_t)t * EE;
  const float* r1 = s_part + (size_t)BB * SS * EE + (size_t)t * EE;
  const float4 a0 = *(const float4*)&r0[lane * 4];
  const float4 a1 = *(const float4*)&r0[256 + lane * 4];
  const float4 c0 = *(const float4*)&r1[lane * 4];
  const float4 c1 = *(const float4*)&r1[256 + lane * 4];
  const float v0x = a0.x + c0.x, v0y = a0.y + c0.y, v0z = a0.z + c0.z, v0w = a0.w + c0.w;
  const float v1x = a1.x + c1.x, v1y = a1.y + c1.y, v1z = a1.z + c1.z, v1w = a1.w + c1.w;
  float m = fmaxf(fmaxf(fmaxf(v0x, v0y), fmaxf(v0z, v0w)),
                  fmaxf(fmaxf(v1x, v1y), fmaxf(v1z, v1w)));
#pragma unroll
  for (int sh = 32; sh > 0; sh >>= 1) m = fmaxf(m, __shfl_xor(m, sh, 64));
  m = fmaxf(m, ss);
  const float e0 = __expf(v0x - m), e1 = __expf(v0y - m);
  const float e2 = __expf(v0z - m), e3 = __expf(v0w - m);
  const float e4 = __expf(v1x - m), e5 = __expf(v1y - m);
  const float e6 = __expf(v1z - m), e7 = __expf(v1w - m);
  float sum = ((e0 + e1) + (e2 + e3)) + ((e4 + e5) + (e6 + e7));
#pragma unroll
  for (int sh = 32; sh > 0; sh >>= 1) sum += __shfl_xor(sum, sh, 64);
  const float es = __expf(ss - m);
  const float inv = 1.0f / (sum + es);
  f16x4 p0, p1;
  p0.x = (f16)(e0 * inv); p0.y = (f16)(e1 * inv);
  p0.z = (f16)(e2 * inv); p0.w = (f16)(e3 * inv);
  p1.x = (f16)(e4 * inv); p1.y = (f16)(e5 * inv);
  p1.z = (f16)(e6 * inv); p1.w = (f16)(e7 * inv);
  *(f16x4*)&probs[(size_t)t * EE + lane * 4] = p0;
  *(f16x4*)&probs[(size_t)t * EE + 256 + lane * 4] = p1;
  if (lane == 0) p_self[t] = es * inv;
}

// PV GEMM per batch: out[b,s,h] = probs[b,s,:] . v_ext[b,:,h] + p_self*v_tok
__global__ __launch_bounds__(256, 4) void pv_kernel(
    const f16* __restrict__ probs, const f16* __restrict__ veT,
    const float* __restrict__ p_self, const f16* __restrict__ vt,
    float* __restrict__ out) {
  const int b = blockIdx.z;
  const int mtile = blockIdx.y;  // 0..15 (S)
  const int ntile = blockIdx.x;  // 0..7  (H)
  __shared__ f16 lds[2 * 4096];
  const size_t aoff = ((size_t)b * SS + mtile * 128) * EE;
  const size_t boff = ((size_t)b * HH + ntile * 128) * EE;

  f32x4 acc[4][4];
#pragma unroll
  for (int i = 0; i < 4; ++i)
#pragma unroll
    for (int j = 0; j < 4; ++j)
#pragma unroll
      for (int r = 0; r < 4; ++r) acc[i][j][r] = 0.0f;

  gemm_core<1>(probs + aoff, nullptr, veT + boff, nullptr, EE, EE,
               lds, nullptr, lds + 4096, nullptr, acc);

  const int tid = threadIdx.x, wave = tid >> 6, lane = tid & 63;
  const int waveM = (wave >> 1) * 64, waveN = (wave & 1) * 64;
  const int colIn16 = lane & 15, rowQuad = (lane >> 4) * 4;
#pragma unroll
  for (int j = 0; j < 4; ++j) {
    const int h = ntile * 128 + waveN + j * 16 + colIn16;
#pragma unroll
    for (int i = 0; i < 4; ++i)
#pragma unroll
      for (int r = 0; r < 4; ++r) {
        const int s = mtile * 128 + waveM + i * 16 + rowQuad + r;
        const size_t t = (size_t)b * SS + s;
        out[t * HH + h] = acc[i][j][r] + p_self[t] * (float)vt[t * HH + h];
      }
  }
}

extern "C" void kernel_launch(void* const* d_in, const int* in_sizes, int n_in,
                              void* d_out, int out_size, void* d_ws, size_t ws_size,
                              hipStream_t stream) {
  const float* hidden = (const float*)d_in[0];
  const float* ext    = (const float*)d_in[1];
  const float* Wq = (const float*)d_in[2];
  const float* bq = (const float*)d_in[3];
  const float* Wk = (const float*)d_in[4];
  const float* bk = (const float*)d_in[5];
  const float* Wv = (const float*)d_in[6];
  const float* bv = (const float*)d_in[7];
  float* out = (float*)d_out;

  char* ws = (char*)d_ws;
  size_t off = 0;
  auto alloc = [&](size_t bytes) {
    char* p = ws + off;
    off += (bytes + 255) & ~(size_t)255;
    return p;
  };
  const size_t TOK = 8192, EXT = 2048;
  f16* xh    = (f16*)alloc(TOK * HH * 2);
  f16* xe    = (f16*)alloc(EXT * HH * 2);
  f16* wt_hi = (f16*)alloc(3072ull * HH * 2);
  f16* wt_lo = (f16*)alloc(3072ull * HH * 2);
  f16* q_hi  = (f16*)alloc(TOK * HH * 2);
  f16* q_lo  = (f16*)alloc(TOK * HH * 2);
  f16* kt    = (f16*)alloc(TOK * HH * 2);
  f16* vt    = (f16*)alloc(TOK * HH * 2);
  f16* ke_hi = (f16*)alloc(EXT * HH * 2);
  f16* ke_lo = (f16*)alloc(EXT * HH * 2);
  f16* veT   = (f16*)alloc((size_t)BB * HH * EE * 2);
  float* p_self = (float*)alloc(TOK * 4);
  float* s_part = (float*)alloc(2ull * BB * SS * EE * 4);
  f16* probs    = (f16*)alloc((size_t)BB * SS * EE * 2);

  // 1. cast A-side inputs to fp16; transpose+split W to fp16 hi/lo
  cast_kernel<<<8192, 256, 0, stream>>>(hidden, xh, (int)(TOK * HH / 4));
  cast_kernel<<<2048, 256, 0, stream>>>(ext, xe, (int)(EXT * HH / 4));
  wsplit_kernel<<<dim3(32, 96), dim3(32, 8), 0, stream>>>(Wq, Wk, Wv, wt_hi, wt_lo);

  // 2. fused projection GEMM (q split, token-k plain, ext-k split, v plain)
  proj_kernel<<<dim3(24, 80), 256, 0, stream>>>(
      xh, xe, wt_hi, wt_lo, bq, bk, bv,
      q_hi, q_lo, kt, vt, ke_hi, ke_lo, veT);

  // 3. attention
  score_kernel<<<dim3(4, 16, 8), 256, 0, stream>>>(q_hi, q_lo, ke_hi, ke_lo, s_part);
  softmax_kernel<<<2048, 256, 0, stream>>>(q_hi, q_lo, kt, s_part, probs, p_self);
  pv_kernel<<<dim3(8, 16, 4), 256, 0, stream>>>(probs, veT, p_self, vt, out);
}

// Round 5
// 360.317 us; speedup vs baseline: 1.2185x; 1.2185x over previous
//
#include <hip/hip_runtime.h>
#include <stdint.h>

// Problem dims (fixed by reference)
#define BB 4
#define SS 2048
#define EE 512
#define HH 1024
// token rows = 8192, ext rows = 2048

typedef _Float16 f16;
typedef __attribute__((ext_vector_type(8))) _Float16 f16x8;
typedef __attribute__((ext_vector_type(4))) _Float16 f16x4;
typedef __attribute__((ext_vector_type(4))) float f32x4;

__device__ __forceinline__ void async16(void* lds, const void* g) {
  __builtin_amdgcn_global_load_lds(
      (const __attribute__((address_space(1))) unsigned int*)g,
      (__attribute__((address_space(3))) unsigned int*)lds, 16, 0, 0);
}

// ---------------------------------------------------------------------------
// Core 128x128 BT-GEMM: C = A * B^T, row-major fp16, row stride = ld.
// TERMS=1: acc += A*Bh          (2 LDS buffers)
// TERMS=2: acc += A*Bh + A*Bl   (3 buffers; B split hi+lo)
// TERMS=3: acc += Ah*Bh + Ah*Bl + Al*Bh  (4 buffers; both split)
// LDS XOR-swizzle: row r's 16B k-chunk c stored at c ^ ((r>>1)&3) ->
// conflict-free ds_read_b128 (verified R2: SQ_LDS_BANK_CONFLICT 1.2e7 -> 0).
// ---------------------------------------------------------------------------
template <int TERMS>
__device__ __forceinline__ void gemm_core(
    const f16* Ah, const f16* Al, const f16* Bh, const f16* Bl, int K, int ld,
    f16* lAh, f16* lAl, f16* lBh, f16* lBl, f32x4 acc[4][4]) {
  const int tid = threadIdx.x;
  const int wave = tid >> 6;
  const int lane = tid & 63;
  const int lrow = lane >> 2;  // 0..15 within 16-row staging group
  const int lcol = (((lane & 3) ^ ((lane >> 3) & 3))) * 8;  // swizzled source chunk
  const int waveM = (wave >> 1) * 64;
  const int waveN = (wave & 1) * 64;
  const int frow = lane & 15;
  const int fk = ((lane >> 4) ^ ((frow >> 1) & 3)) * 8;  // swizzled fragment pos

  for (int k0 = 0; k0 < K; k0 += 32) {
    __syncthreads();  // previous iteration's LDS reads done
#pragma unroll
    for (int i = 0; i < 2; ++i) {
      const int r0 = (wave * 2 + i) * 16;
      const size_t goff = (size_t)(r0 + lrow) * ld + (k0 + lcol);
      async16(&lAh[r0 * 32], Ah + goff);
      async16(&lBh[r0 * 32], Bh + goff);
      if (TERMS >= 2) async16(&lBl[r0 * 32], Bl + goff);
      if (TERMS >= 3) async16(&lAl[r0 * 32], Al + goff);
    }
    __syncthreads();  // staging complete

    f16x8 a[4], bh[4], bl[4], al[4];
#pragma unroll
    for (int i = 0; i < 4; ++i) {
      a[i] = *(const f16x8*)&lAh[(waveM + i * 16 + frow) * 32 + fk];
      bh[i] = *(const f16x8*)&lBh[(waveN + i * 16 + frow) * 32 + fk];
      if (TERMS >= 2) bl[i] = *(const f16x8*)&lBl[(waveN + i * 16 + frow) * 32 + fk];
      if (TERMS >= 3) al[i] = *(const f16x8*)&lAl[(waveM + i * 16 + frow) * 32 + fk];
    }
#pragma unroll
    for (int i = 0; i < 4; ++i)
#pragma unroll
      for (int j = 0; j < 4; ++j) {
        acc[i][j] = __builtin_amdgcn_mfma_f32_16x16x32_f16(a[i], bh[j], acc[i][j], 0, 0, 0);
        if (TERMS >= 2)
          acc[i][j] = __builtin_amdgcn_mfma_f32_16x16x32_f16(a[i], bl[j], acc[i][j], 0, 0, 0);
        if (TERMS >= 3)
          acc[i][j] = __builtin_amdgcn_mfma_f32_16x16x32_f16(al[i], bh[j], acc[i][j], 0, 0, 0);
      }
  }
}

// Transposed epilogue for veT ONLY (fixes the 2B-stride-1KB scatter that
// caused ~up-to-32x write-sector amplification in R2/R3). LDS filled
// transposed ([64 cols][136-row pad]), read back contiguous along e.
// dst pre-offset to (bb*HH + c2base)*EE + e0. Needs 64*136*2 = 17.4 KB.
__device__ __forceinline__ void epi_transposed(
    f16* __restrict__ dst, const f32x4 acc[4][4], const float bias[4], f16* tl) {
  const int tid = threadIdx.x, wave = tid >> 6, lane = tid & 63;
  const int waveM = (wave >> 1) * 64;
  const int colIn16 = lane & 15, quad = lane >> 4;
#pragma unroll
  for (int p = 0; p < 2; ++p) {
    __syncthreads();
    if ((wave & 1) == p) {
#pragma unroll
      for (int i = 0; i < 4; ++i)
#pragma unroll
        for (int j = 0; j < 4; ++j)
#pragma unroll
          for (int r = 0; r < 4; ++r) {
            const int row = waveM + i * 16 + quad * 4 + r;
            const int colL = j * 16 + colIn16;
            tl[colL * 136 + row] = (f16)(acc[i][j][r] + bias[j]);
          }
    }
    __syncthreads();
    for (int c = tid; c < 1024; c += 256) {
      const int colL = c >> 4, ch = c & 15;
      const f16x8 v = *(const f16x8*)&tl[colL * 136 + ch * 8];
      *(f16x8*)&dst[(size_t)(p * 64 + colL) * EE + ch * 8] = v;
    }
  }
}

// fp32 -> fp16 cast (A-side operands need no lo plane)
__global__ __launch_bounds__(256) void cast_kernel(const float* __restrict__ x,
                                                   f16* __restrict__ h, int n4) {
  const int i = blockIdx.x * 256 + threadIdx.x;
  if (i >= n4) return;
  const float4 v = ((const float4*)x)[i];
  f16x4 o;
  o.x = (f16)v.x; o.y = (f16)v.y; o.z = (f16)v.z; o.w = (f16)v.w;
  ((f16x4*)h)[i] = o;
}

// Transpose-split W: Wt[n'][k] = W_{n'>>10}[k][n'&1023], n' in [0,3072), fp16 hi+lo
__global__ void wsplit_kernel(const float* __restrict__ Wq, const float* __restrict__ Wk,
                              const float* __restrict__ Wv, f16* __restrict__ wt_hi,
                              f16* __restrict__ wt_lo) {
  __shared__ float tile[32][33];
  const int k0 = blockIdx.x * 32;
  const int n0g = blockIdx.y * 32;
  const int which = n0g >> 10;
  const float* W = which == 0 ? Wq : (which == 1 ? Wk : Wv);
  const int n0 = n0g & 1023;
  const int tx = threadIdx.x, ty = threadIdx.y;
#pragma unroll
  for (int i = 0; i < 32; i += 8)
    tile[ty + i][tx] = W[(size_t)(k0 + ty + i) * 1024 + n0 + tx];
  __syncthreads();
#pragma unroll
  for (int i = 0; i < 32; i += 8) {
    const int np = n0g + ty + i;
    const float v = tile[tx][ty + i];
    const size_t idx = (size_t)np * 1024 + k0 + tx;
    const f16 h = (f16)v;
    wt_hi[idx] = h;
    wt_lo[idx] = (f16)(v - (float)h);
  }
}

// ---------------------------------------------------------------------------
// Projection GEMM: rows = [8192 token | 2048 ext], cols = [q|k|v].
// Split (B=wt hi+lo): q (token only), ext-k. Plain: token-k (self-dot only),
// all v. Ext rows skip q.
// Linear grid, inner-8-mtile swizzle: consecutive 8 blocks = 8 mtiles (one
// per XCD) sharing one ntile -> XCD j owns mtiles == j (mod 8): A working set
// 2.5 MB/XCD stays L2-hot across all 24 ntiles; B streams from L3.
// Epilogue: scalar stores (R3-proven; L2 merges within-block) except veT.
// ---------------------------------------------------------------------------
__global__ __launch_bounds__(256, 4) void proj_kernel(
    const f16* __restrict__ xh, const f16* __restrict__ xe,
    const f16* __restrict__ wt_hi, const f16* __restrict__ wt_lo,
    const float* __restrict__ bq, const float* __restrict__ bk,
    const float* __restrict__ bv, f16* __restrict__ q_hi, f16* __restrict__ q_lo,
    f16* __restrict__ kt, f16* __restrict__ vt,
    f16* __restrict__ ke_hi, f16* __restrict__ ke_lo, f16* __restrict__ veT) {
  const int g = blockIdx.x;          // 0..1919
  const int grp = g / 192;           // 0..9 (mtile group of 8)
  const int rr_ = g % 192;
  const int mtile = grp * 8 + (rr_ & 7);  // 0..79
  const int ntile = rr_ >> 3;             // 0..23
  const bool extRows = (mtile >= 64);
  if (extRows && ntile < 8) return;  // ext rows need no q

  __shared__ f16 lds[3 * 4096];  // 24 KB: staging (2-3 x 8KB); veT epi reuses

  const f16* A = extRows ? xe : xh;
  const int rowA = (extRows ? (mtile - 64) : mtile) * 128;
  const int rowB = ntile * 128;
  const bool split = (ntile < 8) || (extRows && ntile < 16);

  f32x4 acc[4][4];
#pragma unroll
  for (int i = 0; i < 4; ++i)
#pragma unroll
    for (int j = 0; j < 4; ++j)
#pragma unroll
      for (int r = 0; r < 4; ++r) acc[i][j][r] = 0.0f;

  if (split)
    gemm_core<2>(A + (size_t)rowA * HH, nullptr, wt_hi + (size_t)rowB * HH,
                 wt_lo + (size_t)rowB * HH, HH, HH,
                 lds, nullptr, lds + 4096, lds + 8192, acc);
  else
    gemm_core<1>(A + (size_t)rowA * HH, nullptr, wt_hi + (size_t)rowB * HH,
                 nullptr, HH, HH, lds, nullptr, lds + 4096, nullptr, acc);

  const int tid = threadIdx.x, wave = tid >> 6, lane = tid & 63;
  const int waveM = (wave >> 1) * 64, waveN = (wave & 1) * 64;
  const int colIn16 = lane & 15, rowQuad = (lane >> 4) * 4;
  float bias[4];
#pragma unroll
  for (int j = 0; j < 4; ++j) {
    const int c = ntile * 128 + waveN + j * 16 + colIn16;
    bias[j] = c < 1024 ? bq[c] : (c < 2048 ? bk[c - 1024] : bv[c - 2048]);
  }

  if (extRows && ntile >= 16) {  // veT: transposed LDS epilogue
    const int ge0 = (mtile - 64) * 128;
    const int bb = ge0 >> 9, e0 = ge0 & 511;
    epi_transposed(veT + ((size_t)bb * HH + (ntile - 16) * 128) * EE + e0,
                   acc, bias, lds);
    return;
  }

  // Scalar row-major epilogue (R3-proven)
#pragma unroll
  for (int j = 0; j < 4; ++j) {
    const int c = ntile * 128 + waveN + j * 16 + colIn16;  // 0..3071
#pragma unroll
    for (int i = 0; i < 4; ++i) {
#pragma unroll
      for (int r = 0; r < 4; ++r) {
        const int lrowIdx = waveM + i * 16 + rowQuad + r;  // 0..127
        const float val = acc[i][j][r] + bias[j];
        if (c < 1024) {  // q (token rows only), hi+lo
          const size_t idx = (size_t)(mtile * 128 + lrowIdx) * HH + c;
          const f16 h = (f16)val;
          q_hi[idx] = h;
          q_lo[idx] = (f16)(val - (float)h);
        } else if (c < 2048) {  // k
          const int c2 = c - 1024;
          if (!extRows) {
            kt[(size_t)(mtile * 128 + lrowIdx) * HH + c2] = (f16)val;
          } else {
            const int ge = (mtile - 64) * 128 + lrowIdx;
            const size_t idx = (size_t)ge * HH + c2;
            const f16 h = (f16)val;
            ke_hi[idx] = h;
            ke_lo[idx] = (f16)(val - (float)h);
          }
        } else {  // v (token rows; ext handled above)
          vt[(size_t)(mtile * 128 + lrowIdx) * HH + (c - 2048)] = (f16)val;
        }
      }
    }
  }
}

// Score GEMM, split-K, 3-term: s_part[kh][b][s][e] = q[b,s,kh*512:] . ke[...]
// acc = qh*keh + qh*kel + ql*keh (dropped ql*kel ~ 1e-7 relative).
// s_part is written once / read once -> non-temporal stores.
__global__ __launch_bounds__(256, 4) void score_kernel(
    const f16* __restrict__ q_hi, const f16* __restrict__ q_lo,
    const f16* __restrict__ ke_hi, const f16* __restrict__ ke_lo,
    float* __restrict__ s_part) {
  const int b = blockIdx.z & 3;
  const int khalf = blockIdx.z >> 2;
  const int mtile = blockIdx.y;  // 0..15
  const int ntile = blockIdx.x;  // 0..3
  __shared__ f16 lds[4 * 4096];
  const size_t aoff = ((size_t)b * SS + mtile * 128) * HH + khalf * 512;
  const size_t boff = ((size_t)b * EE + ntile * 128) * HH + khalf * 512;

  f32x4 acc[4][4];
#pragma unroll
  for (int i = 0; i < 4; ++i)
#pragma unroll
    for (int j = 0; j < 4; ++j)
#pragma unroll
      for (int r = 0; r < 4; ++r) acc[i][j][r] = 0.0f;

  gemm_core<3>(q_hi + aoff, q_lo + aoff, ke_hi + boff, ke_lo + boff, 512, HH,
               lds, lds + 4096, lds + 8192, lds + 12288, acc);

  float* dst = s_part + (size_t)khalf * BB * SS * EE;
  const int tid = threadIdx.x, wave = tid >> 6, lane = tid & 63;
  const int waveM = (wave >> 1) * 64, waveN = (wave & 1) * 64;
  const int colIn16 = lane & 15, rowQuad = (lane >> 4) * 4;
#pragma unroll
  for (int j = 0; j < 4; ++j) {
    const int e = ntile * 128 + waveN + j * 16 + colIn16;
#pragma unroll
    for (int i = 0; i < 4; ++i)
#pragma unroll
      for (int r = 0; r < 4; ++r) {
        const int s = mtile * 128 + waveM + i * 16 + rowQuad + r;
        __builtin_nontemporal_store(acc[i][j][r],
                                    &dst[((size_t)b * SS + s) * EE + e]);
      }
  }
}

// Fused selfdot + softmax: s_self = (q_hi+q_lo).kt (fp32 accumulate),
// softmax over [s_self, s_part0+s_part1]; probs -> fp16, p_self -> fp32.
__global__ __launch_bounds__(256) void softmax_kernel(
    const f16* __restrict__ q_hi, const f16* __restrict__ q_lo,
    const f16* __restrict__ kt, const float* __restrict__ s_part,
    f16* __restrict__ probs, float* __restrict__ p_self) {
  const int t = blockIdx.x * 4 + (threadIdx.x >> 6);
  const int lane = threadIdx.x & 63;

  // selfdot
  const size_t base = (size_t)t * HH;
  float ss = 0.f;
#pragma unroll
  for (int it = 0; it < 4; ++it) {
    const int off = it * 256 + lane * 4;
    const f16x4 qh = *(const f16x4*)&q_hi[base + off];
    const f16x4 ql = *(const f16x4*)&q_lo[base + off];
    const f16x4 kh = *(const f16x4*)&kt[base + off];
    ss += ((float)qh.x + (float)ql.x) * (float)kh.x;
    ss += ((float)qh.y + (float)ql.y) * (float)kh.y;
    ss += ((float)qh.z + (float)ql.z) * (float)kh.z;
    ss += ((float)qh.w + (float)ql.w) * (float)kh.w;
  }
#pragma unroll
  for (int m = 32; m > 0; m >>= 1) ss += __shfl_xor(ss, m, 64);

  // softmax over 1 + 512 (s_part: read-once -> non-temporal loads)
  const float* r0 = s_part + (size_t)t * EE;
  const float* r1 = s_part + (size_t)BB * SS * EE + (size_t)t * EE;
  const f32x4 a0 = __builtin_nontemporal_load((const f32x4*)&r0[lane * 4]);
  const f32x4 a1 = __builtin_nontemporal_load((const f32x4*)&r0[256 + lane * 4]);
  const f32x4 c0 = __builtin_nontemporal_load((const f32x4*)&r1[lane * 4]);
  const f32x4 c1 = __builtin_nontemporal_load((const f32x4*)&r1[256 + lane * 4]);
  const float v0x = a0.x + c0.x, v0y = a0.y + c0.y, v0z = a0.z + c0.z, v0w = a0.w + c0.w;
  const float v1x = a1.x + c1.x, v1y = a1.y + c1.y, v1z = a1.z + c1.z, v1w = a1.w + c1.w;
  float m = fmaxf(fmaxf(fmaxf(v0x, v0y), fmaxf(v0z, v0w)),
                  fmaxf(fmaxf(v1x, v1y), fmaxf(v1z, v1w)));
#pragma unroll
  for (int sh = 32; sh > 0; sh >>= 1) m = fmaxf(m, __shfl_xor(m, sh, 64));
  m = fmaxf(m, ss);
  const float e0 = __expf(v0x - m), e1 = __expf(v0y - m);
  const float e2 = __expf(v0z - m), e3 = __expf(v0w - m);
  const float e4 = __expf(v1x - m), e5 = __expf(v1y - m);
  const float e6 = __expf(v1z - m), e7 = __expf(v1w - m);
  float sum = ((e0 + e1) + (e2 + e3)) + ((e4 + e5) + (e6 + e7));
#pragma unroll
  for (int sh = 32; sh > 0; sh >>= 1) sum += __shfl_xor(sum, sh, 64);
  const float es = __expf(ss - m);
  const float inv = 1.0f / (sum + es);
  f16x4 p0, p1;
  p0.x = (f16)(e0 * inv); p0.y = (f16)(e1 * inv);
  p0.z = (f16)(e2 * inv); p0.w = (f16)(e3 * inv);
  p1.x = (f16)(e4 * inv); p1.y = (f16)(e5 * inv);
  p1.z = (f16)(e6 * inv); p1.w = (f16)(e7 * inv);
  *(f16x4*)&probs[(size_t)t * EE + lane * 4] = p0;
  *(f16x4*)&probs[(size_t)t * EE + 256 + lane * 4] = p1;
  if (lane == 0) p_self[t] = es * inv;
}

// PV GEMM per batch: out[b,s,h] = probs[b,s,:] . v_ext[b,:,h] + p_self*v_tok
// out is never re-read -> non-temporal stores.
__global__ __launch_bounds__(256, 4) void pv_kernel(
    const f16* __restrict__ probs, const f16* __restrict__ veT,
    const float* __restrict__ p_self, const f16* __restrict__ vt,
    float* __restrict__ out) {
  const int b = blockIdx.z;
  const int mtile = blockIdx.y;  // 0..15 (S)
  const int ntile = blockIdx.x;  // 0..7  (H)
  __shared__ f16 lds[2 * 4096];
  const size_t aoff = ((size_t)b * SS + mtile * 128) * EE;
  const size_t boff = ((size_t)b * HH + ntile * 128) * EE;

  f32x4 acc[4][4];
#pragma unroll
  for (int i = 0; i < 4; ++i)
#pragma unroll
    for (int j = 0; j < 4; ++j)
#pragma unroll
      for (int r = 0; r < 4; ++r) acc[i][j][r] = 0.0f;

  gemm_core<1>(probs + aoff, nullptr, veT + boff, nullptr, EE, EE,
               lds, nullptr, lds + 4096, nullptr, acc);

  const int tid = threadIdx.x, wave = tid >> 6, lane = tid & 63;
  const int waveM = (wave >> 1) * 64, waveN = (wave & 1) * 64;
  const int colIn16 = lane & 15, rowQuad = (lane >> 4) * 4;
#pragma unroll
  for (int j = 0; j < 4; ++j) {
    const int h = ntile * 128 + waveN + j * 16 + colIn16;
#pragma unroll
    for (int i = 0; i < 4; ++i)
#pragma unroll
      for (int r = 0; r < 4; ++r) {
        const int s = mtile * 128 + waveM + i * 16 + rowQuad + r;
        const size_t t = (size_t)b * SS + s;
        __builtin_nontemporal_store(
            acc[i][j][r] + p_self[t] * (float)vt[t * HH + h], &out[t * HH + h]);
      }
  }
}

extern "C" void kernel_launch(void* const* d_in, const int* in_sizes, int n_in,
                              void* d_out, int out_size, void* d_ws, size_t ws_size,
                              hipStream_t stream) {
  const float* hidden = (const float*)d_in[0];
  const float* ext    = (const float*)d_in[1];
  const float* Wq = (const float*)d_in[2];
  const float* bq = (const float*)d_in[3];
  const float* Wk = (const float*)d_in[4];
  const float* bk = (const float*)d_in[5];
  const float* Wv = (const float*)d_in[6];
  const float* bv = (const float*)d_in[7];
  float* out = (float*)d_out;

  char* ws = (char*)d_ws;
  size_t off = 0;
  auto alloc = [&](size_t bytes) {
    char* p = ws + off;
    off += (bytes + 255) & ~(size_t)255;
    return p;
  };
  const size_t TOK = 8192, EXT = 2048;
  f16* xh    = (f16*)alloc(TOK * HH * 2);
  f16* xe    = (f16*)alloc(EXT * HH * 2);
  f16* wt_hi = (f16*)alloc(3072ull * HH * 2);
  f16* wt_lo = (f16*)alloc(3072ull * HH * 2);
  f16* q_hi  = (f16*)alloc(TOK * HH * 2);
  f16* q_lo  = (f16*)alloc(TOK * HH * 2);
  f16* kt    = (f16*)alloc(TOK * HH * 2);
  f16* vt    = (f16*)alloc(TOK * HH * 2);
  f16* ke_hi = (f16*)alloc(EXT * HH * 2);
  f16* ke_lo = (f16*)alloc(EXT * HH * 2);
  f16* veT   = (f16*)alloc((size_t)BB * HH * EE * 2);
  float* p_self = (float*)alloc(TOK * 4);
  float* s_part = (float*)alloc(2ull * BB * SS * EE * 4);
  f16* probs    = (f16*)alloc((size_t)BB * SS * EE * 2);

  // 1. cast A-side inputs to fp16; transpose+split W to fp16 hi/lo
  cast_kernel<<<8192, 256, 0, stream>>>(hidden, xh, (int)(TOK * HH / 4));
  cast_kernel<<<2048, 256, 0, stream>>>(ext, xe, (int)(EXT * HH / 4));
  wsplit_kernel<<<dim3(32, 96), dim3(32, 8), 0, stream>>>(Wq, Wk, Wv, wt_hi, wt_lo);

  // 2. fused projection GEMM (linear grid, inner-8-mtile XCD swizzle)
  proj_kernel<<<1920, 256, 0, stream>>>(
      xh, xe, wt_hi, wt_lo, bq, bk, bv,
      q_hi, q_lo, kt, vt, ke_hi, ke_lo, veT);

  // 3. attention
  score_kernel<<<dim3(4, 16, 8), 256, 0, stream>>>(q_hi, q_lo, ke_hi, ke_lo, s_part);
  softmax_kernel<<<2048, 256, 0, stream>>>(q_hi, q_lo, kt, s_part, probs, p_self);
  pv_kernel<<<dim3(8, 16, 4), 256, 0, stream>>>(probs, veT, p_self, vt, out);
}

// Round 6
// 332.492 us; speedup vs baseline: 1.3205x; 1.0837x over previous
//
#include <hip/hip_runtime.h>
#include <stdint.h>

// Problem dims (fixed by reference)
#define BB 4
#define SS 2048
#define EE 512
#define HH 1024
// token rows = 8192, ext rows = 2048

typedef _Float16 f16;
typedef __attribute__((ext_vector_type(8))) _Float16 f16x8;
typedef __attribute__((ext_vector_type(4))) _Float16 f16x4;
typedef __attribute__((ext_vector_type(4))) float f32x4;

__device__ __forceinline__ void async16(void* lds, const void* g) {
  __builtin_amdgcn_global_load_lds(
      (const __attribute__((address_space(1))) unsigned int*)g,
      (__attribute__((address_space(3))) unsigned int*)lds, 16, 0, 0);
}

// ---------------------------------------------------------------------------
// Core 128x128 BT-GEMM: C = A * B^T, row-major fp16, row stride = ld.
// TERMS=1: acc += A*Bh          (2 LDS buffers)
// TERMS=2: acc += A*Bh + A*Bl   (3 buffers; B split hi+lo)
// TERMS=3: acc += Ah*Bh + Ah*Bl + Al*Bh  (4 buffers; both split)
// LDS XOR-swizzle: row r's 16B k-chunk c stored at c ^ ((r>>1)&3) ->
// conflict-free ds_read_b128 (verified R2: SQ_LDS_BANK_CONFLICT 1.2e7 -> 0).
// ---------------------------------------------------------------------------
template <int TERMS>
__device__ __forceinline__ void gemm_core(
    const f16* Ah, const f16* Al, const f16* Bh, const f16* Bl, int K, int ld,
    f16* lAh, f16* lAl, f16* lBh, f16* lBl, f32x4 acc[4][4]) {
  const int tid = threadIdx.x;
  const int wave = tid >> 6;
  const int lane = tid & 63;
  const int lrow = lane >> 2;  // 0..15 within 16-row staging group
  const int lcol = (((lane & 3) ^ ((lane >> 3) & 3))) * 8;  // swizzled source chunk
  const int waveM = (wave >> 1) * 64;
  const int waveN = (wave & 1) * 64;
  const int frow = lane & 15;
  const int fk = ((lane >> 4) ^ ((frow >> 1) & 3)) * 8;  // swizzled fragment pos

  for (int k0 = 0; k0 < K; k0 += 32) {
    __syncthreads();  // previous iteration's LDS reads done
#pragma unroll
    for (int i = 0; i < 2; ++i) {
      const int r0 = (wave * 2 + i) * 16;
      const size_t goff = (size_t)(r0 + lrow) * ld + (k0 + lcol);
      async16(&lAh[r0 * 32], Ah + goff);
      async16(&lBh[r0 * 32], Bh + goff);
      if (TERMS >= 2) async16(&lBl[r0 * 32], Bl + goff);
      if (TERMS >= 3) async16(&lAl[r0 * 32], Al + goff);
    }
    __syncthreads();  // staging complete

    f16x8 a[4], bh[4], bl[4], al[4];
#pragma unroll
    for (int i = 0; i < 4; ++i) {
      a[i] = *(const f16x8*)&lAh[(waveM + i * 16 + frow) * 32 + fk];
      bh[i] = *(const f16x8*)&lBh[(waveN + i * 16 + frow) * 32 + fk];
      if (TERMS >= 2) bl[i] = *(const f16x8*)&lBl[(waveN + i * 16 + frow) * 32 + fk];
      if (TERMS >= 3) al[i] = *(const f16x8*)&lAl[(waveM + i * 16 + frow) * 32 + fk];
    }
#pragma unroll
    for (int i = 0; i < 4; ++i)
#pragma unroll
      for (int j = 0; j < 4; ++j) {
        acc[i][j] = __builtin_amdgcn_mfma_f32_16x16x32_f16(a[i], bh[j], acc[i][j], 0, 0, 0);
        if (TERMS >= 2)
          acc[i][j] = __builtin_amdgcn_mfma_f32_16x16x32_f16(a[i], bl[j], acc[i][j], 0, 0, 0);
        if (TERMS >= 3)
          acc[i][j] = __builtin_amdgcn_mfma_f32_16x16x32_f16(al[i], bh[j], acc[i][j], 0, 0, 0);
      }
  }
}

// Transposed epilogue for veT ONLY (fixes the 2B-stride-1KB scatter that
// caused ~up-to-32x write-sector amplification in R2/R3). LDS filled
// transposed ([64 cols][136-row pad]), read back contiguous along e.
__device__ __forceinline__ void epi_transposed(
    f16* __restrict__ dst, const f32x4 acc[4][4], const float bias[4], f16* tl) {
  const int tid = threadIdx.x, wave = tid >> 6, lane = tid & 63;
  const int waveM = (wave >> 1) * 64;
  const int colIn16 = lane & 15, quad = lane >> 4;
#pragma unroll
  for (int p = 0; p < 2; ++p) {
    __syncthreads();
    if ((wave & 1) == p) {
#pragma unroll
      for (int i = 0; i < 4; ++i)
#pragma unroll
        for (int j = 0; j < 4; ++j)
#pragma unroll
          for (int r = 0; r < 4; ++r) {
            const int row = waveM + i * 16 + quad * 4 + r;
            const int colL = j * 16 + colIn16;
            tl[colL * 136 + row] = (f16)(acc[i][j][r] + bias[j]);
          }
    }
    __syncthreads();
    for (int c = tid; c < 1024; c += 256) {
      const int colL = c >> 4, ch = c & 15;
      const f16x8 v = *(const f16x8*)&tl[colL * 136 + ch * 8];
      *(f16x8*)&dst[(size_t)(p * 64 + colL) * EE + ch * 8] = v;
    }
  }
}

// fp32 -> fp16 cast, both inputs in one launch (hidden then ext)
__global__ __launch_bounds__(256) void cast_kernel(const float* __restrict__ xh32,
                                                   const float* __restrict__ xe32,
                                                   f16* __restrict__ xh,
                                                   f16* __restrict__ xe) {
  const int i = blockIdx.x * 256 + threadIdx.x;
  const int n4h = 8192 * HH / 4;
  const float* src = i < n4h ? xh32 : xe32;
  f16* dst = i < n4h ? xh : xe;
  const int k = i < n4h ? i : i - n4h;
  const float4 v = ((const float4*)src)[k];
  f16x4 o;
  o.x = (f16)v.x; o.y = (f16)v.y; o.z = (f16)v.z; o.w = (f16)v.w;
  ((f16x4*)dst)[k] = o;
}

// Transpose-split W: Wt[n'][k] = W_{n'>>10}[k][n'&1023], n' in [0,3072), fp16 hi+lo
__global__ void wsplit_kernel(const float* __restrict__ Wq, const float* __restrict__ Wk,
                              const float* __restrict__ Wv, f16* __restrict__ wt_hi,
                              f16* __restrict__ wt_lo) {
  __shared__ float tile[32][33];
  const int k0 = blockIdx.x * 32;
  const int n0g = blockIdx.y * 32;
  const int which = n0g >> 10;
  const float* W = which == 0 ? Wq : (which == 1 ? Wk : Wv);
  const int n0 = n0g & 1023;
  const int tx = threadIdx.x, ty = threadIdx.y;
#pragma unroll
  for (int i = 0; i < 32; i += 8)
    tile[ty + i][tx] = W[(size_t)(k0 + ty + i) * 1024 + n0 + tx];
  __syncthreads();
#pragma unroll
  for (int i = 0; i < 32; i += 8) {
    const int np = n0g + ty + i;
    const float v = tile[tx][ty + i];
    const size_t idx = (size_t)np * 1024 + k0 + tx;
    const f16 h = (f16)v;
    wt_hi[idx] = h;
    wt_lo[idx] = (f16)(v - (float)h);
  }
}

// ---------------------------------------------------------------------------
// Projection GEMM: rows = [8192 token | 2048 ext], cols = [q|k|v].
// Split (B=wt hi+lo): q (token only), ext-k. Plain: token-k, all v.
// Grid order (assumes round-robin block->XCD = g%8): per-XCD sequence is
// [ntile-window of 2] x [its mtiles] x [2] so the concurrent L2 footprint is
// A (2.5 MB, 10 mtiles) + B (~1.5 MB, 2 ntiles) <= 4 MB -> A re-reads and
// B re-reads hit L2 instead of thrashing it (R5: 24 live ntiles = ~10 MB of
// streaming B evicted A continuously, FETCH stayed 208 MB).
// Grid 1792: token 8x(12 win x 8 mt x 2) + ext 8x(8 win x 2 mt x 2).
// ---------------------------------------------------------------------------
__global__ __launch_bounds__(256, 4) void proj_kernel(
    const f16* __restrict__ xh, const f16* __restrict__ xe,
    const f16* __restrict__ wt_hi, const f16* __restrict__ wt_lo,
    const float* __restrict__ bq, const float* __restrict__ bk,
    const float* __restrict__ bv, f16* __restrict__ q_hi, f16* __restrict__ q_lo,
    f16* __restrict__ kt, f16* __restrict__ vt,
    f16* __restrict__ ke_hi, f16* __restrict__ ke_lo, f16* __restrict__ veT) {
  const int g = blockIdx.x;  // 0..1791
  const int j = g & 7;       // XCD (round-robin assumption)
  const int s = g >> 3;      // 0..223 per-XCD sequence
  int mtile, ntile;
  if (s < 192) {  // token rows
    const int w = s / 16, r = s % 16;
    ntile = w * 2 + (r & 1);
    mtile = (r >> 1) * 8 + j;
  } else {  // ext rows (no q)
    const int s2 = s - 192;
    const int w = s2 >> 2, r = s2 & 3;
    ntile = 8 + w * 2 + (r & 1);
    mtile = 64 + (r >> 1) * 8 + j;
  }
  const bool extRows = (mtile >= 64);

  __shared__ f16 lds[3 * 4096];  // 24 KB: staging; veT epi reuses

  const f16* A = extRows ? xe : xh;
  const int rowA = (extRows ? (mtile - 64) : mtile) * 128;
  const int rowB = ntile * 128;
  const bool split = (ntile < 8) || (extRows && ntile < 16);

  f32x4 acc[4][4];
#pragma unroll
  for (int i = 0; i < 4; ++i)
#pragma unroll
    for (int jj = 0; jj < 4; ++jj)
#pragma unroll
      for (int r = 0; r < 4; ++r) acc[i][jj][r] = 0.0f;

  if (split)
    gemm_core<2>(A + (size_t)rowA * HH, nullptr, wt_hi + (size_t)rowB * HH,
                 wt_lo + (size_t)rowB * HH, HH, HH,
                 lds, nullptr, lds + 4096, lds + 8192, acc);
  else
    gemm_core<1>(A + (size_t)rowA * HH, nullptr, wt_hi + (size_t)rowB * HH,
                 nullptr, HH, HH, lds, nullptr, lds + 4096, nullptr, acc);

  const int tid = threadIdx.x, wave = tid >> 6, lane = tid & 63;
  const int waveM = (wave >> 1) * 64, waveN = (wave & 1) * 64;
  const int colIn16 = lane & 15, rowQuad = (lane >> 4) * 4;
  float bias[4];
#pragma unroll
  for (int jj = 0; jj < 4; ++jj) {
    const int c = ntile * 128 + waveN + jj * 16 + colIn16;
    bias[jj] = c < 1024 ? bq[c] : (c < 2048 ? bk[c - 1024] : bv[c - 2048]);
  }

  if (extRows && ntile >= 16) {  // veT: transposed LDS epilogue
    const int ge0 = (mtile - 64) * 128;
    const int bb = ge0 >> 9, e0 = ge0 & 511;
    epi_transposed(veT + ((size_t)bb * HH + (ntile - 16) * 128) * EE + e0,
                   acc, bias, lds);
    return;
  }

  // Scalar row-major epilogue (R3-proven; R4's LDS repack regressed)
#pragma unroll
  for (int jj = 0; jj < 4; ++jj) {
    const int c = ntile * 128 + waveN + jj * 16 + colIn16;  // 0..3071
#pragma unroll
    for (int i = 0; i < 4; ++i) {
#pragma unroll
      for (int r = 0; r < 4; ++r) {
        const int lrowIdx = waveM + i * 16 + rowQuad + r;  // 0..127
        const float val = acc[i][jj][r] + bias[jj];
        if (c < 1024) {  // q (token rows only), hi+lo
          const size_t idx = (size_t)(mtile * 128 + lrowIdx) * HH + c;
          const f16 h = (f16)val;
          q_hi[idx] = h;
          q_lo[idx] = (f16)(val - (float)h);
        } else if (c < 2048) {  // k
          const int c2 = c - 1024;
          if (!extRows) {
            kt[(size_t)(mtile * 128 + lrowIdx) * HH + c2] = (f16)val;
          } else {
            const int ge = (mtile - 64) * 128 + lrowIdx;
            const size_t idx = (size_t)ge * HH + c2;
            const f16 h = (f16)val;
            ke_hi[idx] = h;
            ke_lo[idx] = (f16)(val - (float)h);
          }
        } else {  // v (token rows; ext handled above)
          vt[(size_t)(mtile * 128 + lrowIdx) * HH + (c - 2048)] = (f16)val;
        }
      }
    }
  }
}

// Score GEMM, split-K, 3-term: s_part[kh][b][s][e] = q[b,s,kh*512:] . ke[...]
// acc = qh*keh + qh*kel + ql*keh (dropped ql*kel ~ 1e-7 relative).
// s_part stays temporal: written-then-read-soon, L3 (256 MB) absorbs it
// (R5's nt hints streamed it to HBM).
__global__ __launch_bounds__(256, 4) void score_kernel(
    const f16* __restrict__ q_hi, const f16* __restrict__ q_lo,
    const f16* __restrict__ ke_hi, const f16* __restrict__ ke_lo,
    float* __restrict__ s_part) {
  const int b = blockIdx.z & 3;
  const int khalf = blockIdx.z >> 2;
  const int mtile = blockIdx.y;  // 0..15
  const int ntile = blockIdx.x;  // 0..3
  __shared__ f16 lds[4 * 4096];
  const size_t aoff = ((size_t)b * SS + mtile * 128) * HH + khalf * 512;
  const size_t boff = ((size_t)b * EE + ntile * 128) * HH + khalf * 512;

  f32x4 acc[4][4];
#pragma unroll
  for (int i = 0; i < 4; ++i)
#pragma unroll
    for (int j = 0; j < 4; ++j)
#pragma unroll
      for (int r = 0; r < 4; ++r) acc[i][j][r] = 0.0f;

  gemm_core<3>(q_hi + aoff, q_lo + aoff, ke_hi + boff, ke_lo + boff, 512, HH,
               lds, lds + 4096, lds + 8192, lds + 12288, acc);

  float* dst = s_part + (size_t)khalf * BB * SS * EE;
  const int tid = threadIdx.x, wave = tid >> 6, lane = tid & 63;
  const int waveM = (wave >> 1) * 64, waveN = (wave & 1) * 64;
  const int colIn16 = lane & 15, rowQuad = (lane >> 4) * 4;
#pragma unroll
  for (int j = 0; j < 4; ++j) {
    const int e = ntile * 128 + waveN + j * 16 + colIn16;
#pragma unroll
    for (int i = 0; i < 4; ++i)
#pragma unroll
      for (int r = 0; r < 4; ++r) {
        const int s = mtile * 128 + waveM + i * 16 + rowQuad + r;
        dst[((size_t)b * SS + s) * EE + e] = acc[i][j][r];
      }
  }
}

// Fused selfdot + softmax: s_self = (q_hi+q_lo).kt (fp32 accumulate),
// softmax over [s_self, s_part0+s_part1]; probs -> fp16, p_self -> fp32.
__global__ __launch_bounds__(256) void softmax_kernel(
    const f16* __restrict__ q_hi, const f16* __restrict__ q_lo,
    const f16* __restrict__ kt, const float* __restrict__ s_part,
    f16* __restrict__ probs, float* __restrict__ p_self) {
  const int t = blockIdx.x * 4 + (threadIdx.x >> 6);
  const int lane = threadIdx.x & 63;

  // selfdot
  const size_t base = (size_t)t * HH;
  float ss = 0.f;
#pragma unroll
  for (int it = 0; it < 4; ++it) {
    const int off = it * 256 + lane * 4;
    const f16x4 qh = *(const f16x4*)&q_hi[base + off];
    const f16x4 ql = *(const f16x4*)&q_lo[base + off];
    const f16x4 kh = *(const f16x4*)&kt[base + off];
    ss += ((float)qh.x + (float)ql.x) * (float)kh.x;
    ss += ((float)qh.y + (float)ql.y) * (float)kh.y;
    ss += ((float)qh.z + (float)ql.z) * (float)kh.z;
    ss += ((float)qh.w + (float)ql.w) * (float)kh.w;
  }
#pragma unroll
  for (int m = 32; m > 0; m >>= 1) ss += __shfl_xor(ss, m, 64);

  // softmax over 1 + 512
  const float* r0 = s_part + (size_t)t * EE;
  const float* r1 = s_part + (size_t)BB * SS * EE + (size_t)t * EE;
  const float4 a0 = *(const float4*)&r0[lane * 4];
  const float4 a1 = *(const float4*)&r0[256 + lane * 4];
  const float4 c0 = *(const float4*)&r1[lane * 4];
  const float4 c1 = *(const float4*)&r1[256 + lane * 4];
  const float v0x = a0.x + c0.x, v0y = a0.y + c0.y, v0z = a0.z + c0.z, v0w = a0.w + c0.w;
  const float v1x = a1.x + c1.x, v1y = a1.y + c1.y, v1z = a1.z + c1.z, v1w = a1.w + c1.w;
  float m = fmaxf(fmaxf(fmaxf(v0x, v0y), fmaxf(v0z, v0w)),
                  fmaxf(fmaxf(v1x, v1y), fmaxf(v1z, v1w)));
#pragma unroll
  for (int sh = 32; sh > 0; sh >>= 1) m = fmaxf(m, __shfl_xor(m, sh, 64));
  m = fmaxf(m, ss);
  const float e0 = __expf(v0x - m), e1 = __expf(v0y - m);
  const float e2 = __expf(v0z - m), e3 = __expf(v0w - m);
  const float e4 = __expf(v1x - m), e5 = __expf(v1y - m);
  const float e6 = __expf(v1z - m), e7 = __expf(v1w - m);
  float sum = ((e0 + e1) + (e2 + e3)) + ((e4 + e5) + (e6 + e7));
#pragma unroll
  for (int sh = 32; sh > 0; sh >>= 1) sum += __shfl_xor(sum, sh, 64);
  const float es = __expf(ss - m);
  const float inv = 1.0f / (sum + es);
  f16x4 p0, p1;
  p0.x = (f16)(e0 * inv); p0.y = (f16)(e1 * inv);
  p0.z = (f16)(e2 * inv); p0.w = (f16)(e3 * inv);
  p1.x = (f16)(e4 * inv); p1.y = (f16)(e5 * inv);
  p1.z = (f16)(e6 * inv); p1.w = (f16)(e7 * inv);
  *(f16x4*)&probs[(size_t)t * EE + lane * 4] = p0;
  *(f16x4*)&probs[(size_t)t * EE + 256 + lane * 4] = p1;
  if (lane == 0) p_self[t] = es * inv;
}

// PV GEMM per batch: out[b,s,h] = probs[b,s,:] . v_ext[b,:,h] + p_self*v_tok
// out is never re-read -> non-temporal stores (keep).
__global__ __launch_bounds__(256, 4) void pv_kernel(
    const f16* __restrict__ probs, const f16* __restrict__ veT,
    const float* __restrict__ p_self, const f16* __restrict__ vt,
    float* __restrict__ out) {
  const int b = blockIdx.z;
  const int mtile = blockIdx.y;  // 0..15 (S)
  const int ntile = blockIdx.x;  // 0..7  (H)
  __shared__ f16 lds[2 * 4096];
  const size_t aoff = ((size_t)b * SS + mtile * 128) * EE;
  const size_t boff = ((size_t)b * HH + ntile * 128) * EE;

  f32x4 acc[4][4];
#pragma unroll
  for (int i = 0; i < 4; ++i)
#pragma unroll
    for (int j = 0; j < 4; ++j)
#pragma unroll
      for (int r = 0; r < 4; ++r) acc[i][j][r] = 0.0f;

  gemm_core<1>(probs + aoff, nullptr, veT + boff, nullptr, EE, EE,
               lds, nullptr, lds + 4096, nullptr, acc);

  const int tid = threadIdx.x, wave = tid >> 6, lane = tid & 63;
  const int waveM = (wave >> 1) * 64, waveN = (wave & 1) * 64;
  const int colIn16 = lane & 15, rowQuad = (lane >> 4) * 4;
#pragma unroll
  for (int j = 0; j < 4; ++j) {
    const int h = ntile * 128 + waveN + j * 16 + colIn16;
#pragma unroll
    for (int i = 0; i < 4; ++i)
#pragma unroll
      for (int r = 0; r < 4; ++r) {
        const int s = mtile * 128 + waveM + i * 16 + rowQuad + r;
        const size_t t = (size_t)b * SS + s;
        __builtin_nontemporal_store(
            acc[i][j][r] + p_self[t] * (float)vt[t * HH + h], &out[t * HH + h]);
      }
  }
}

extern "C" void kernel_launch(void* const* d_in, const int* in_sizes, int n_in,
                              void* d_out, int out_size, void* d_ws, size_t ws_size,
                              hipStream_t stream) {
  const float* hidden = (const float*)d_in[0];
  const float* ext    = (const float*)d_in[1];
  const float* Wq = (const float*)d_in[2];
  const float* bq = (const float*)d_in[3];
  const float* Wk = (const float*)d_in[4];
  const float* bk = (const float*)d_in[5];
  const float* Wv = (const float*)d_in[6];
  const float* bv = (const float*)d_in[7];
  float* out = (float*)d_out;

  char* ws = (char*)d_ws;
  size_t off = 0;
  auto alloc = [&](size_t bytes) {
    char* p = ws + off;
    off += (bytes + 255) & ~(size_t)255;
    return p;
  };
  const size_t TOK = 8192, EXT = 2048;
  f16* xh    = (f16*)alloc(TOK * HH * 2);
  f16* xe    = (f16*)alloc(EXT * HH * 2);
  f16* wt_hi = (f16*)alloc(3072ull * HH * 2);
  f16* wt_lo = (f16*)alloc(3072ull * HH * 2);
  f16* q_hi  = (f16*)alloc(TOK * HH * 2);
  f16* q_lo  = (f16*)alloc(TOK * HH * 2);
  f16* kt    = (f16*)alloc(TOK * HH * 2);
  f16* vt    = (f16*)alloc(TOK * HH * 2);
  f16* ke_hi = (f16*)alloc(EXT * HH * 2);
  f16* ke_lo = (f16*)alloc(EXT * HH * 2);
  f16* veT   = (f16*)alloc((size_t)BB * HH * EE * 2);
  float* p_self = (float*)alloc(TOK * 4);
  float* s_part = (float*)alloc(2ull * BB * SS * EE * 4);
  f16* probs    = (f16*)alloc((size_t)BB * SS * EE * 2);

  // 1. cast A-side inputs to fp16 (one launch); transpose+split W hi/lo
  cast_kernel<<<10240, 256, 0, stream>>>(hidden, ext, xh, xe);
  wsplit_kernel<<<dim3(32, 96), dim3(32, 8), 0, stream>>>(Wq, Wk, Wv, wt_hi, wt_lo);

  // 2. fused projection GEMM (L2-window-ordered grid, 1792 blocks)
  proj_kernel<<<1792, 256, 0, stream>>>(
      xh, xe, wt_hi, wt_lo, bq, bk, bv,
      q_hi, q_lo, kt, vt, ke_hi, ke_lo, veT);

  // 3. attention
  score_kernel<<<dim3(4, 16, 8), 256, 0, stream>>>(q_hi, q_lo, ke_hi, ke_lo, s_part);
  softmax_kernel<<<2048, 256, 0, stream>>>(q_hi, q_lo, kt, s_part, probs, p_self);
  pv_kernel<<<dim3(8, 16, 4), 256, 0, stream>>>(probs, veT, p_self, vt, out);
}